// Round 2
// baseline (210.002 us; speedup 1.0000x reference)
//
#include <hip/hip_runtime.h>
#include <hip/hip_fp16.h>

#define BS 4
#define NSEQ 2048
#define C_ 8
#define D_ 128
#define E_ 256
#define TWO_E 512
#define CHUNK 64
#define NCH (NSEQ / CHUNK) /* 32 */

typedef __attribute__((ext_vector_type(8))) short short8;
typedef __attribute__((ext_vector_type(8))) _Float16 half8;
typedef __attribute__((ext_vector_type(4))) float floatx4;

// Round fp32 -> bf16 grid (RNE), return as fp32. Matches np/jax bf16 cast.
// The harness's np reference computes from bf16-cast inputs in fp32; we must
// quantize identically at every input touch point.
__device__ __forceinline__ float bfr(float f) {
    unsigned int u = __float_as_uint(f);
    u = (u + 0x7FFFu + ((u >> 16) & 1u)) & 0xFFFF0000u;
    return __uint_as_float(u);
}
__device__ __forceinline__ unsigned short f2h(float f) {
    return __half_as_ushort(__float2half(f));  // v_cvt_f16_f32, RNE
}
__device__ __forceinline__ float h2f(unsigned short h) {
    return __half2float(__ushort_as_half(h));
}
__device__ __forceinline__ float sigmoidf_(float v) {
    return 1.0f / (1.0f + __expf(-v));
}
__device__ __forceinline__ floatx4 mfma16(short8 a, short8 b, floatx4 c) {
    return __builtin_amdgcn_mfma_f32_16x16x32_f16(
        __builtin_bit_cast(half8, a), __builtin_bit_cast(half8, b), c, 0, 0, 0);
}

// LayerNorm of a 64-row chunk into LDS fp16 hi/lo tiles (stride 136 shorts).
// x, gamma, beta are rounded to the bf16 grid first (ref parity); the LN
// output v is carried as fp16 hi + fp16 lo => ~2^-24 relative accuracy.
__device__ __forceinline__ void layernorm_tile(
    const float* __restrict__ x, const float* __restrict__ gamma, const float* __restrict__ beta,
    int b, int c, int n0, int tid,
    unsigned short* __restrict__ xh, unsigned short* __restrict__ xl)
{
    const int r = tid >> 2;
    const int p = tid & 3;
    const float* xrow = x + ((size_t)((b * NSEQ + n0 + r) * C_) + c) * D_;
    float4 xv[8];
    float s = 0.f, ss = 0.f;
    #pragma unroll
    for (int i = 0; i < 8; i++) {
        float4 t = ((const float4*)xrow)[p + 4 * i];
        t.x = bfr(t.x); t.y = bfr(t.y); t.z = bfr(t.z); t.w = bfr(t.w);
        xv[i] = t;
        s += t.x + t.y + t.z + t.w;
        ss += t.x * t.x + t.y * t.y + t.z * t.z + t.w * t.w;
    }
    s += __shfl_xor(s, 1);  s += __shfl_xor(s, 2);
    ss += __shfl_xor(ss, 1); ss += __shfl_xor(ss, 2);
    const float mu = s * (1.0f / D_);
    const float rsig = rsqrtf(fmaxf(ss * (1.0f / D_) - mu * mu, 0.f) + 1e-5f);
    #pragma unroll
    for (int i = 0; i < 8; i++) {
        const int f = p + 4 * i;
        float4 g  = ((const float4*)(gamma + c * D_))[f];
        float4 bt = ((const float4*)(beta + c * D_))[f];
        ushort4 oh, ol;
        {
            const float v = (xv[i].x - mu) * rsig * bfr(g.x) + bfr(bt.x);
            oh.x = f2h(v); ol.x = f2h(v - h2f(oh.x));
        }
        {
            const float v = (xv[i].y - mu) * rsig * bfr(g.y) + bfr(bt.y);
            oh.y = f2h(v); ol.y = f2h(v - h2f(oh.y));
        }
        {
            const float v = (xv[i].z - mu) * rsig * bfr(g.z) + bfr(bt.z);
            oh.z = f2h(v); ol.z = f2h(v - h2f(oh.z));
        }
        {
            const float v = (xv[i].w - mu) * rsig * bfr(g.w) + bfr(bt.w);
            oh.w = f2h(v); ol.w = f2h(v - h2f(oh.w));
        }
        *(ushort4*)&xh[r * 136 + 4 * f] = oh;
        *(ushort4*)&xl[r * 136 + 4 * f] = ol;
    }
}

// wT_in[c][e2][d] = fp16(bf16(w_in[c][d][e2]));  bf16-grid values are exactly
// representable in fp16 => exact parity with the reference's bf16 weights.
__global__ __launch_bounds__(256) void k_transpose_win(const float* __restrict__ w,
                                                       unsigned short* __restrict__ wt) {
    __shared__ float tile[32][33];
    const int c = blockIdx.z;
    const int d0 = blockIdx.y * 32;
    const int e0 = blockIdx.x * 32;
    const int tx = threadIdx.x, ty = threadIdx.y;
    #pragma unroll
    for (int k = 0; k < 4; k++)
        tile[ty + k * 8][tx] = w[((size_t)(c * D_ + d0 + ty + k * 8)) * TWO_E + e0 + tx];
    __syncthreads();
    #pragma unroll
    for (int k = 0; k < 4; k++)
        wt[((size_t)(c * TWO_E + e0 + ty + k * 8)) * D_ + d0 + tx] = f2h(bfr(tile[tx][ty + k * 8]));
}

// wT_out[c][d][e] = fp16(bf16(w_out[c][e][d]));
__global__ __launch_bounds__(256) void k_transpose_wout(const float* __restrict__ w,
                                                        unsigned short* __restrict__ wt) {
    __shared__ float tile[32][33];
    const int c = blockIdx.z;
    const int e0 = blockIdx.y * 32;
    const int d0 = blockIdx.x * 32;
    const int tx = threadIdx.x, ty = threadIdx.y;
    #pragma unroll
    for (int k = 0; k < 4; k++)
        tile[ty + k * 8][tx] = w[((size_t)(c * E_ + e0 + ty + k * 8)) * D_ + d0 + tx];
    __syncthreads();
    #pragma unroll
    for (int k = 0; k < 4; k++)
        wt[((size_t)(c * D_ + d0 + ty + k * 8)) * E_ + e0 + tx] = f2h(bfr(tile[tx][ty + k * 8]));
}

// K1: LN + GEMM-in (fp16 hi/lo A-operand) + activations + chunk transform
// composed IN REGISTERS. MFMA chain order (m outer; A-hi, A-lo, B-hi, B-lo)
// MUST match K3 so activations are bitwise identical.
__global__ __launch_bounds__(256) void k1_agg(
    const float* __restrict__ x, const float* __restrict__ gamma, const float* __restrict__ beta,
    const unsigned short* __restrict__ wt_in, const float* __restrict__ b_in,
    float* __restrict__ aggA, float* __restrict__ aggB)
{
    constexpr int LDA = 136;
    __shared__ unsigned short xh[CHUNK * LDA];
    __shared__ unsigned short xl[CHUNK * LDA];

    const int gid = blockIdx.x;
    const int j = gid & (NCH - 1);
    const int c = (gid >> 5) & (C_ - 1);
    const int b = gid >> 8;
    const int n0 = j * CHUNK;
    const int tid = threadIdx.x;

    layernorm_tile(x, gamma, beta, b, c, n0, tid, xh, xl);
    __syncthreads();

    const int wave = tid >> 6;
    const int lane = tid & 63;
    const int lrow = lane & 15;
    const int quad = lane >> 4;

    const unsigned short* wbi = wt_in + (size_t)c * TWO_E * D_;
    const size_t aggbase = ((size_t)(b * C_ + c) * NCH + j) * E_;

    #pragma unroll
    for (int p = 0; p < 4; p++) {
        const int ea = wave * 64 + p * 16 + lrow;
        const int eb = E_ + ea;
        short8 bfa[4], bfb[4];
        #pragma unroll
        for (int k = 0; k < 4; k++) {
            bfa[k] = *(const short8*)&wbi[(size_t)ea * D_ + k * 32 + quad * 8];
            bfb[k] = *(const short8*)&wbi[(size_t)eb * D_ + k * 32 + quad * 8];
        }
        floatx4 accA[4], accB[4];
        #pragma unroll
        for (int m = 0; m < 4; m++) { accA[m] = (floatx4){0,0,0,0}; accB[m] = (floatx4){0,0,0,0}; }
        #pragma unroll
        for (int m = 0; m < 4; m++) {
            short8 ah[4], al[4];
            #pragma unroll
            for (int k = 0; k < 4; k++) {
                ah[k] = *(const short8*)&xh[(m * 16 + lrow) * LDA + k * 32 + quad * 8];
                al[k] = *(const short8*)&xl[(m * 16 + lrow) * LDA + k * 32 + quad * 8];
            }
            #pragma unroll
            for (int k = 0; k < 4; k++) accA[m] = mfma16(ah[k], bfa[k], accA[m]);
            #pragma unroll
            for (int k = 0; k < 4; k++) accA[m] = mfma16(al[k], bfa[k], accA[m]);
            #pragma unroll
            for (int k = 0; k < 4; k++) accB[m] = mfma16(ah[k], bfb[k], accB[m]);
            #pragma unroll
            for (int k = 0; k < 4; k++) accB[m] = mfma16(al[k], bfb[k], accB[m]);
        }
        const float biasa = bfr(b_in[c * TWO_E + ea]);
        const float biasb = bfr(b_in[c * TWO_E + eb]);

        float Ac = 1.f, Bc = 0.f;
        #pragma unroll
        for (int m = 0; m < 4; m++) {
            float A = 1.f, B = 0.f;
            #pragma unroll
            for (int rr = 0; rr < 4; rr++) {
                const float av = sigmoidf_(accA[m][rr] + biasa);
                const float rv = accB[m][rr] + biasb;
                const float bv = rv * sigmoidf_(rv);
                A = av * A;
                B = av * B + bv;
            }
            #pragma unroll
            for (int s = 16; s <= 32; s <<= 1) {
                const float Ap = __shfl_xor(A, s);
                const float Bp = __shfl_xor(B, s);
                B = (lane & s) ? (A * Bp + B) : (Ap * B + Bp);
                A = A * Ap;
            }
            Bc = A * Bc + B;
            Ac = A * Ac;
        }
        if (quad == 0) {
            aggA[aggbase + ea] = Ac;
            aggB[aggbase + ea] = Bc;
        }
    }
}

// K2: sequential scan over the 32 chunk aggregates; seeds with bf16(h_prev).
__global__ __launch_bounds__(256) void k2_scan_chunks(
    const float* __restrict__ h_prev, const float* __restrict__ aggA, const float* __restrict__ aggB,
    float* __restrict__ hin, float* __restrict__ h_last)
{
    const int bc = blockIdx.x;
    const int e = threadIdx.x;
    float h = bfr(h_prev[(size_t)bc * E_ + e]);
    const size_t base = (size_t)bc * NCH * E_ + e;
    #pragma unroll
    for (int jj = 0; jj < NCH; jj++) {
        hin[base + (size_t)jj * E_] = h;
        h = aggA[base + (size_t)jj * E_] * h + aggB[base + (size_t)jj * E_];
    }
    h_last[(size_t)bc * E_ + e] = h;
}

// K3: LN + GEMM-in (recomputed, bitwise == K1) + fp32 scan + K-split GEMM-out
//     + bias + residual. Four quarter-passes of 64 E-columns; (a,b) stay fp32
//     in LDS. LDS: xh 17408 + xl 17408 + abq 33280 + hq 8704 = 76800 B
//     (2 blocks/CU within 160 KiB).
__global__ __launch_bounds__(256) void k3_fused(
    const float* __restrict__ x, const float* __restrict__ gamma, const float* __restrict__ beta,
    const unsigned short* __restrict__ wt_in, const float* __restrict__ b_in,
    const float* __restrict__ hin,
    const unsigned short* __restrict__ wt_out, const float* __restrict__ b_out,
    float* __restrict__ out)
{
    constexpr int LDX = 136;   // xh/xl stride (shorts), persistent all quarters
    constexpr int LDAB = 65;   // abq stride (float2)
    constexpr int LDQ = 68;    // hq stride (shorts)
    __shared__ unsigned short xh[CHUNK * LDX];
    __shared__ unsigned short xl[CHUNK * LDX];
    __shared__ float2 abq[CHUNK * LDAB];
    __shared__ unsigned short hq[CHUNK * LDQ];

    const int gid = blockIdx.x;
    const int j = gid & (NCH - 1);
    const int c = (gid >> 5) & (C_ - 1);
    const int b = gid >> 8;
    const int n0 = j * CHUNK;
    const int tid = threadIdx.x;

    layernorm_tile(x, gamma, beta, b, c, n0, tid, xh, xl);
    __syncthreads();

    const int wave = tid >> 6;
    const int lane = tid & 63;
    const int lrow = lane & 15;
    const int quad = lane >> 4;
    const int m0 = wave * 16;

    const unsigned short* wbi = wt_in + (size_t)c * TWO_E * D_;
    const unsigned short* wbo = wt_out + (size_t)c * D_ * E_;
    const size_t hinbase = ((size_t)(b * C_ + c) * NCH + j) * E_;

    floatx4 acco[8];
    #pragma unroll
    for (int nt = 0; nt < 8; nt++) acco[nt] = (floatx4){0, 0, 0, 0};

    #pragma unroll
    for (int q = 0; q < 4; q++) {
        // ---- GEMM-in: this wave's 16 matched a/b column pairs of quarter q ----
        {
            const int eq = wave * 16 + lrow;          // column within quarter [0,64)
            const int ea = q * 64 + eq;
            const int eb = E_ + ea;
            short8 bfa[4], bfb[4];
            #pragma unroll
            for (int k = 0; k < 4; k++) {
                bfa[k] = *(const short8*)&wbi[(size_t)ea * D_ + k * 32 + quad * 8];
                bfb[k] = *(const short8*)&wbi[(size_t)eb * D_ + k * 32 + quad * 8];
            }
            floatx4 accA[4], accB[4];
            #pragma unroll
            for (int m = 0; m < 4; m++) { accA[m] = (floatx4){0,0,0,0}; accB[m] = (floatx4){0,0,0,0}; }
            #pragma unroll
            for (int m = 0; m < 4; m++) {
                short8 ah[4], al[4];
                #pragma unroll
                for (int k = 0; k < 4; k++) {
                    ah[k] = *(const short8*)&xh[(m * 16 + lrow) * LDX + k * 32 + quad * 8];
                    al[k] = *(const short8*)&xl[(m * 16 + lrow) * LDX + k * 32 + quad * 8];
                }
                #pragma unroll
                for (int k = 0; k < 4; k++) accA[m] = mfma16(ah[k], bfa[k], accA[m]);
                #pragma unroll
                for (int k = 0; k < 4; k++) accA[m] = mfma16(al[k], bfa[k], accA[m]);
                #pragma unroll
                for (int k = 0; k < 4; k++) accB[m] = mfma16(ah[k], bfb[k], accB[m]);
                #pragma unroll
                for (int k = 0; k < 4; k++) accB[m] = mfma16(al[k], bfb[k], accB[m]);
            }
            const float biasa = bfr(b_in[c * TWO_E + ea]);
            const float biasb = bfr(b_in[c * TWO_E + eb]);
            #pragma unroll
            for (int m = 0; m < 4; m++)
                #pragma unroll
                for (int rr = 0; rr < 4; rr++) {
                    const int row = m * 16 + quad * 4 + rr;
                    const float av = sigmoidf_(accA[m][rr] + biasa);
                    const float rv = accB[m][rr] + biasb;
                    const float bv = rv * sigmoidf_(rv);
                    abq[row * LDAB + eq] = make_float2(av, bv);
                }
        }
        __syncthreads();  // abq ready; prior quarter's abq reads done (pre-sync)

        // ---- fp32 scan: 64 threads, one column each ----
        if (tid < 64) {
            float h = hin[hinbase + q * 64 + tid];
            #pragma unroll
            for (int i = 0; i < CHUNK; i++) {
                const float2 v = abq[i * LDAB + tid];
                h = v.x * h + v.y;
                hq[i * LDQ + tid] = f2h(h);
            }
        }
        __syncthreads();  // hq ready; prior quarter's hq reads done (pre-sync)

        // ---- GEMM-out partial accumulation over K-slice [64q, 64q+64) ----
        short8 af2[2];
        #pragma unroll
        for (int k = 0; k < 2; k++)
            af2[k] = *(const short8*)&hq[(m0 + lrow) * LDQ + k * 32 + quad * 8];
        #pragma unroll
        for (int nt = 0; nt < 8; nt++) {
            const int d = nt * 16 + lrow;
            short8 bf2_[2];
            #pragma unroll
            for (int k = 0; k < 2; k++)
                bf2_[k] = *(const short8*)&wbo[(size_t)d * E_ + q * 64 + k * 32 + quad * 8];
            #pragma unroll
            for (int k = 0; k < 2; k++)
                acco[nt] = mfma16(af2[k], bf2_[k], acco[nt]);
        }
        // next quarter's "abq ready" sync orders abq/hq overwrites after these reads
    }

    // ---- epilogue: bias + residual (x rounded to bf16 grid, ref parity) ----
    #pragma unroll
    for (int nt = 0; nt < 8; nt++) {
        const int d = nt * 16 + lrow;
        const float bias = bfr(b_out[c * D_ + d]);
        #pragma unroll
        for (int rr = 0; rr < 4; rr++) {
            const int row = m0 + quad * 4 + rr;
            const size_t xi = ((size_t)((b * NSEQ + n0 + row) * C_) + c) * D_ + d;
            out[xi] = acco[nt][rr] + bias + bfr(x[xi]);
        }
    }
}

extern "C" void kernel_launch(void* const* d_in, const int* in_sizes, int n_in,
                              void* d_out, int out_size, void* d_ws, size_t ws_size,
                              hipStream_t stream) {
    (void)in_sizes; (void)n_in; (void)out_size; (void)ws_size;
    const float* x      = (const float*)d_in[0];
    const float* h_prev = (const float*)d_in[1];
    const float* gamma  = (const float*)d_in[2];
    const float* beta   = (const float*)d_in[3];
    const float* w_in   = (const float*)d_in[4];
    const float* b_in   = (const float*)d_in[5];
    const float* w_out  = (const float*)d_in[6];
    const float* b_out  = (const float*)d_in[7];

    float* out    = (float*)d_out;                        // [BS,N,C,D]
    float* h_last = out + (size_t)BS * NSEQ * C_ * D_;    // [BS,C,E]

    float* ws = (float*)d_ws;
    size_t off = 0;
    float* aggA = ws + off; off += (size_t)BS * C_ * NCH * E_;   // 262,144 f
    float* aggB = ws + off; off += (size_t)BS * C_ * NCH * E_;
    float* hin  = ws + off; off += (size_t)BS * C_ * NCH * E_;
    unsigned short* wt_in  = (unsigned short*)(ws + off); off += (size_t)C_ * TWO_E * D_ / 2;
    unsigned short* wt_out = (unsigned short*)(ws + off); off += (size_t)C_ * D_ * E_ / 2;

    k_transpose_win <<<dim3(16, 4, 8), dim3(32, 8), 0, stream>>>(w_in, wt_in);
    k_transpose_wout<<<dim3(4, 8, 8),  dim3(32, 8), 0, stream>>>(w_out, wt_out);
    k1_agg          <<<BS * C_ * NCH, 256, 0, stream>>>(x, gamma, beta, wt_in, b_in, aggA, aggB);
    k2_scan_chunks  <<<BS * C_, 256, 0, stream>>>(h_prev, aggA, aggB, hin, h_last);
    k3_fused        <<<BS * C_ * NCH, 256, 0, stream>>>(x, gamma, beta, wt_in, b_in,
                                                        hin, wt_out, b_out, out);
}